// Round 2
// baseline (442.509 us; speedup 1.0000x reference)
//
#include <hip/hip_runtime.h>
#include <hip/hip_bf16.h>

typedef __bf16 bf16x8 __attribute__((ext_vector_type(8)));
typedef float f32x4 __attribute__((ext_vector_type(4)));

// Problem constants: B=2, S=2048, D=1024, H=16, HD=64
#define NB 2
#define NS 2048
#define ND 1024
#define NH 16
#define NHD 64

__device__ __forceinline__ unsigned short f2b(float f) {
    union { __hip_bfloat16 h; unsigned short u; } c;
    c.h = __float2bfloat16(f);
    return c.u;
}

__device__ __forceinline__ void cvt16(const float4& v0, const float4& v1,
                                      const float4& v2, const float4& v3,
                                      unsigned short* dst) {
    alignas(16) unsigned short t[16];
    t[0] = f2b(v0.x); t[1] = f2b(v0.y); t[2]  = f2b(v0.z); t[3]  = f2b(v0.w);
    t[4] = f2b(v1.x); t[5] = f2b(v1.y); t[6]  = f2b(v1.z); t[7]  = f2b(v1.w);
    t[8] = f2b(v2.x); t[9] = f2b(v2.y); t[10] = f2b(v2.z); t[11] = f2b(v2.w);
    t[12] = f2b(v3.x); t[13] = f2b(v3.y); t[14] = f2b(v3.z); t[15] = f2b(v3.w);
    *(uint4*)dst = *(const uint4*)&t[0];
    *((uint4*)dst + 1) = *(const uint4*)&t[8];
}

// ---------------------------------------------------------------------------
// Mask dtype probe: jax bool may arrive as 1-byte bool OR 4-byte int/float.
// 4-byte: every dword is 0, 1, or 0x3F800000 (float 1.0). Packed random 0/1
// BYTES fail that test almost immediately (dwords like 0x00010100).
// flag = 1 -> 4-byte elements ("dword != 0 means masked"), 0 -> 1-byte.
// ---------------------------------------------------------------------------
__global__ void detect_mask(const unsigned* __restrict__ m, int* __restrict__ flag) {
    __shared__ int bad;
    if (threadIdx.x == 0) bad = 0;
    __syncthreads();
    int mybad = 0;
    for (int i = threadIdx.x; i < 8192; i += 256) {
        unsigned w = m[i];
        if (w != 0u && w != 1u && w != 0x3F800000u) mybad = 1;
    }
    if (mybad) bad = 1;   // racy store, all writers store 1
    __syncthreads();
    if (threadIdx.x == 0) *flag = bad ? 0 : 1;
}

// ---------------------------------------------------------------------------
// QKV projection: C[i][j] = sum_k x[i][k]*W[j][k] + bias[j]  (y = x @ W.T + b)
// Q,K stored [B,H,S,HD] bf16; V stored transposed [B,H,HD,S] bf16.
// 128x128 tile, 4 waves, each wave 64x64 (4x4 of 16x16x32 MFMA), BK=32.
// ---------------------------------------------------------------------------
__global__ __launch_bounds__(256) void qkv_gemm(
    const float* __restrict__ x,
    const float* __restrict__ Wq, const float* __restrict__ bq,
    const float* __restrict__ Wk, const float* __restrict__ bk,
    const float* __restrict__ Wv, const float* __restrict__ bv,
    unsigned short* __restrict__ Qb, unsigned short* __restrict__ Kb,
    unsigned short* __restrict__ Vtb)
{
    __shared__ alignas(16) unsigned short Alds[128][32];
    __shared__ alignas(16) unsigned short Blds[128][32];

    const int tid  = threadIdx.x;
    const int wave = tid >> 6;
    const int lane = tid & 63;
    const int z    = blockIdx.z;

    const float* W    = (z == 0) ? Wq : (z == 1) ? Wk : Wv;
    const float* bias = (z == 0) ? bq : (z == 1) ? bk : bv;

    const int m0 = blockIdx.x * 128;   // rows of x  (b*s index)
    const int n0 = blockIdx.y * 128;   // output features
    const int wr = (wave >> 1) * 64;
    const int wc = (wave & 1) * 64;

    const int srow = tid >> 1;
    const int scol = (tid & 1) * 16;
    const float* xsrc = x + (size_t)(m0 + srow) * ND + scol;
    const float* wsrc = W + (size_t)(n0 + srow) * ND + scol;

    const int lg = lane >> 4;     // 0..3
    const int ll = lane & 15;
    const int kcol = lg * 8;      // k offset within BK=32

    f32x4 acc[4][4] = {};

    for (int kt = 0; kt < ND; kt += 32) {
        float4 a0 = *(const float4*)(xsrc + kt);
        float4 a1 = *(const float4*)(xsrc + kt + 4);
        float4 a2 = *(const float4*)(xsrc + kt + 8);
        float4 a3 = *(const float4*)(xsrc + kt + 12);
        float4 b0 = *(const float4*)(wsrc + kt);
        float4 b1 = *(const float4*)(wsrc + kt + 4);
        float4 b2 = *(const float4*)(wsrc + kt + 8);
        float4 b3 = *(const float4*)(wsrc + kt + 12);

        if (kt != 0) __syncthreads();
        cvt16(a0, a1, a2, a3, &Alds[srow][scol]);
        cvt16(b0, b1, b2, b3, &Blds[srow][scol]);
        __syncthreads();

        bf16x8 af[4], bfr[4];
        #pragma unroll
        for (int m = 0; m < 4; m++)
            af[m] = *(const bf16x8*)&Alds[wr + m * 16 + ll][kcol];
        #pragma unroll
        for (int n = 0; n < 4; n++)
            bfr[n] = *(const bf16x8*)&Blds[wc + n * 16 + ll][kcol];

        #pragma unroll
        for (int m = 0; m < 4; m++)
            #pragma unroll
            for (int n = 0; n < 4; n++)
                acc[m][n] = __builtin_amdgcn_mfma_f32_16x16x32_bf16(
                    af[m], bfr[n], acc[m][n], 0, 0, 0);
    }

    #pragma unroll
    for (int n = 0; n < 4; n++) {
        const int j  = n0 + wc + n * 16 + ll;
        const float bj = bias[j];
        const int hh = j >> 6;
        const int hd = j & 63;
        #pragma unroll
        for (int m = 0; m < 4; m++) {
            #pragma unroll
            for (int r = 0; r < 4; r++) {
                const int i  = m0 + wr + m * 16 + lg * 4 + r;
                const int bb = i >> 11;
                const int ss = i & 2047;
                const unsigned short o = f2b(acc[m][n][r] + bj);
                if (z == 2) {
                    Vtb[((size_t)(bb * NH + hh) * NHD + hd) * NS + ss] = o;
                } else {
                    const size_t idx = ((size_t)(bb * NH + hh) * NS + ss) * NHD + hd;
                    if (z == 0) Qb[idx] = o; else Kb[idx] = o;
                }
            }
        }
    }
}

// ---------------------------------------------------------------------------
// Flash attention: one wave per 16 q-rows, 4 waves/block.
// K/V read straight from global (512KB/head -> L2 resident).
// ---------------------------------------------------------------------------
__global__ __launch_bounds__(256) void attn_kernel(
    const unsigned short* __restrict__ Qb, const unsigned short* __restrict__ Kb,
    const unsigned short* __restrict__ Vtb, const void* __restrict__ mask,
    const int* __restrict__ mflag, float* __restrict__ out)
{
    __shared__ alignas(16) unsigned short Plds[4][16][32];

    const int tid  = threadIdx.x;
    const int wave = tid >> 6;
    const int lane = tid & 63;
    const int b = blockIdx.z;
    const int h = blockIdx.y;
    const int q0 = blockIdx.x * 64 + wave * 16;

    const int mask4 = *mflag;   // wave-uniform
    const unsigned short* Qp = Qb  + (size_t)(b * NH + h) * NS * NHD;
    const unsigned short* Kp = Kb  + (size_t)(b * NH + h) * NS * NHD;
    const unsigned short* Vp = Vtb + (size_t)(b * NH + h) * NHD * NS;
    const unsigned char* mp8  = (const unsigned char*)mask + (size_t)b * NS * NS;
    const unsigned*      mp32 = (const unsigned*)mask      + (size_t)b * NS * NS;

    const int lg = lane >> 4;
    const int ll = lane & 15;
    const int kcol = lg * 8;

    const bf16x8 qf0 = *(const bf16x8*)&Qp[(q0 + ll) * NHD + kcol];
    const bf16x8 qf1 = *(const bf16x8*)&Qp[(q0 + ll) * NHD + 32 + kcol];

    f32x4 O0 = {}, O1 = {}, O2 = {}, O3 = {};
    float mrun[4] = {-3.0e38f, -3.0e38f, -3.0e38f, -3.0e38f};
    float lrun[4] = {0.f, 0.f, 0.f, 0.f};

    const float scale = 0.03125f;  // 1/sqrt(1024)

    for (int kb = 0; kb < NS; kb += 32) {
        f32x4 s4_0 = {}, s4_1 = {};
        {
            bf16x8 kf0 = *(const bf16x8*)&Kp[(kb + ll) * NHD + kcol];
            bf16x8 kf1 = *(const bf16x8*)&Kp[(kb + ll) * NHD + 32 + kcol];
            s4_0 = __builtin_amdgcn_mfma_f32_16x16x32_bf16(qf0, kf0, s4_0, 0, 0, 0);
            s4_0 = __builtin_amdgcn_mfma_f32_16x16x32_bf16(qf1, kf1, s4_0, 0, 0, 0);
        }
        {
            bf16x8 kf0 = *(const bf16x8*)&Kp[(kb + 16 + ll) * NHD + kcol];
            bf16x8 kf1 = *(const bf16x8*)&Kp[(kb + 16 + ll) * NHD + 32 + kcol];
            s4_1 = __builtin_amdgcn_mfma_f32_16x16x32_bf16(qf0, kf0, s4_1, 0, 0, 0);
            s4_1 = __builtin_amdgcn_mfma_f32_16x16x32_bf16(qf1, kf1, s4_1, 0, 0, 0);
        }

        #pragma unroll
        for (int r = 0; r < 4; r++) {
            const int q = q0 + lg * 4 + r;
            const size_t mi = (size_t)q * NS + kb + ll;
            unsigned mb0, mb1;
            if (mask4) { mb0 = (mp32[mi] != 0u); mb1 = (mp32[mi + 16] != 0u); }
            else       { mb0 = mp8[mi];          mb1 = mp8[mi + 16]; }
            float sv0 = mb0 ? -1e9f : s4_0[r] * scale;
            float sv1 = mb1 ? -1e9f : s4_1[r] * scale;

            float mt = fmaxf(sv0, sv1);
            mt = fmaxf(mt, __shfl_xor(mt, 1));
            mt = fmaxf(mt, __shfl_xor(mt, 2));
            mt = fmaxf(mt, __shfl_xor(mt, 4));
            mt = fmaxf(mt, __shfl_xor(mt, 8));

            const float mnew  = fmaxf(mrun[r], mt);
            const float alpha = __expf(mrun[r] - mnew);
            const float p0 = __expf(sv0 - mnew);
            const float p1 = __expf(sv1 - mnew);

            float rs = p0 + p1;
            rs += __shfl_xor(rs, 1);
            rs += __shfl_xor(rs, 2);
            rs += __shfl_xor(rs, 4);
            rs += __shfl_xor(rs, 8);

            lrun[r] = lrun[r] * alpha + rs;
            mrun[r] = mnew;
            O0[r] *= alpha; O1[r] *= alpha; O2[r] *= alpha; O3[r] *= alpha;

            Plds[wave][lg * 4 + r][ll]      = f2b(p0);
            Plds[wave][lg * 4 + r][16 + ll] = f2b(p1);
        }

        const bf16x8 pa = *(const bf16x8*)&Plds[wave][ll][kcol];
        const bf16x8 vf0 = *(const bf16x8*)&Vp[(size_t)(0 * 16 + ll) * NS + kb + kcol];
        const bf16x8 vf1 = *(const bf16x8*)&Vp[(size_t)(1 * 16 + ll) * NS + kb + kcol];
        const bf16x8 vf2 = *(const bf16x8*)&Vp[(size_t)(2 * 16 + ll) * NS + kb + kcol];
        const bf16x8 vf3 = *(const bf16x8*)&Vp[(size_t)(3 * 16 + ll) * NS + kb + kcol];
        O0 = __builtin_amdgcn_mfma_f32_16x16x32_bf16(pa, vf0, O0, 0, 0, 0);
        O1 = __builtin_amdgcn_mfma_f32_16x16x32_bf16(pa, vf1, O1, 0, 0, 0);
        O2 = __builtin_amdgcn_mfma_f32_16x16x32_bf16(pa, vf2, O2, 0, 0, 0);
        O3 = __builtin_amdgcn_mfma_f32_16x16x32_bf16(pa, vf3, O3, 0, 0, 0);
    }

    #pragma unroll
    for (int r = 0; r < 4; r++) {
        const int q = q0 + lg * 4 + r;
        const float inv = 1.0f / lrun[r];
        float* op = out + (size_t)(b * NS + q) * ND + h * NHD;
        op[0 * 16 + ll] = O0[r] * inv;
        op[1 * 16 + ll] = O1[r] * inv;
        op[2 * 16 + ll] = O2[r] * inv;
        op[3 * 16 + ll] = O3[r] * inv;
    }
}

extern "C" void kernel_launch(void* const* d_in, const int* in_sizes, int n_in,
                              void* d_out, int out_size, void* d_ws, size_t ws_size,
                              hipStream_t stream)
{
    const float* x  = (const float*)d_in[0];
    const void* mask = d_in[1];
    const float* Wq = (const float*)d_in[2];
    const float* bq = (const float*)d_in[3];
    const float* Wk = (const float*)d_in[4];
    const float* bk = (const float*)d_in[5];
    const float* Wv = (const float*)d_in[6];
    const float* bv = (const float*)d_in[7];
    float* out = (float*)d_out;

    int* mflag = (int*)d_ws;
    unsigned short* Qb  = (unsigned short*)((char*)d_ws + 256);   // 8MB
    unsigned short* Kb  = Qb + (size_t)NB * NH * NS * NHD;        // 8MB
    unsigned short* Vtb = Kb + (size_t)NB * NH * NS * NHD;        // 8MB (transposed)

    dim3 blk(256);
    detect_mask<<<dim3(1), blk, 0, stream>>>((const unsigned*)mask, mflag);

    dim3 g1(32, 8, 3);
    qkv_gemm<<<g1, blk, 0, stream>>>(x, Wq, bq, Wk, bk, Wv, bv, Qb, Kb, Vtb);

    dim3 g2(NS / 64, NH, NB);
    attn_kernel<<<g2, blk, 0, stream>>>(Qb, Kb, Vtb, mask, mflag, out);
}

// Round 3
// 429.715 us; speedup vs baseline: 1.0298x; 1.0298x over previous
//
#include <hip/hip_runtime.h>
#include <hip/hip_bf16.h>

typedef __bf16 bf16x8 __attribute__((ext_vector_type(8)));
typedef float f32x4 __attribute__((ext_vector_type(4)));

// Problem constants: B=2, S=2048, D=1024, H=16, HD=64
#define NB 2
#define NS 2048
#define ND 1024
#define NH 16
#define NHD 64

__device__ __forceinline__ unsigned short f2b(float f) {
    union { __hip_bfloat16 h; unsigned short u; } c;
    c.h = __float2bfloat16(f);
    return c.u;
}

__device__ __forceinline__ void cvt16(const float4& v0, const float4& v1,
                                      const float4& v2, const float4& v3,
                                      unsigned short* dst) {
    alignas(16) unsigned short t[16];
    t[0] = f2b(v0.x); t[1] = f2b(v0.y); t[2]  = f2b(v0.z); t[3]  = f2b(v0.w);
    t[4] = f2b(v1.x); t[5] = f2b(v1.y); t[6]  = f2b(v1.z); t[7]  = f2b(v1.w);
    t[8] = f2b(v2.x); t[9] = f2b(v2.y); t[10] = f2b(v2.z); t[11] = f2b(v2.w);
    t[12] = f2b(v3.x); t[13] = f2b(v3.y); t[14] = f2b(v3.z); t[15] = f2b(v3.w);
    *(uint4*)dst = *(const uint4*)&t[0];
    *((uint4*)dst + 1) = *(const uint4*)&t[8];
}

// ---------------------------------------------------------------------------
// Mask dtype probe (unchanged from round 1 — it picked correctly).
// flag = 1 -> 4-byte elements, 0 -> 1-byte.
// ---------------------------------------------------------------------------
__global__ void detect_mask(const unsigned* __restrict__ m, int* __restrict__ flag) {
    __shared__ int bad;
    if (threadIdx.x == 0) bad = 0;
    __syncthreads();
    int mybad = 0;
    for (int i = threadIdx.x; i < 8192; i += 256) {
        unsigned w = m[i];
        if (w != 0u && w != 1u && w != 0x3F800000u) mybad = 1;
    }
    if (mybad) bad = 1;
    __syncthreads();
    if (threadIdx.x == 0) *flag = bad ? 0 : 1;
}

// ---------------------------------------------------------------------------
// Bit-pack the mask: B*S*S elements -> B*S*S/64 u64 words (1 MB, L2-resident).
// One wave produces one word via __ballot. Grid = words/4 blocks of 4 waves.
// ---------------------------------------------------------------------------
__global__ __launch_bounds__(256) void pack_mask(
    const void* __restrict__ mask, const int* __restrict__ mflag,
    unsigned long long* __restrict__ mbits)
{
    const int wave = threadIdx.x >> 6;
    const int lane = threadIdx.x & 63;
    const size_t w = (size_t)blockIdx.x * 4 + wave;
    const size_t e = w * 64 + lane;
    int v;
    if (*mflag) v = (((const unsigned*)mask)[e] != 0u);
    else        v = (((const unsigned char*)mask)[e] != 0);
    unsigned long long bits = __ballot(v);
    if (lane == 0) mbits[w] = bits;
}

// ---------------------------------------------------------------------------
// QKV projection (unchanged): y = x @ W.T + b
// Q,K stored [B,H,S,HD] bf16; V stored transposed [B,H,HD,S] bf16.
// ---------------------------------------------------------------------------
__global__ __launch_bounds__(256) void qkv_gemm(
    const float* __restrict__ x,
    const float* __restrict__ Wq, const float* __restrict__ bq,
    const float* __restrict__ Wk, const float* __restrict__ bk,
    const float* __restrict__ Wv, const float* __restrict__ bv,
    unsigned short* __restrict__ Qb, unsigned short* __restrict__ Kb,
    unsigned short* __restrict__ Vtb)
{
    __shared__ alignas(16) unsigned short Alds[128][32];
    __shared__ alignas(16) unsigned short Blds[128][32];

    const int tid  = threadIdx.x;
    const int wave = tid >> 6;
    const int lane = tid & 63;
    const int z    = blockIdx.z;

    const float* W    = (z == 0) ? Wq : (z == 1) ? Wk : Wv;
    const float* bias = (z == 0) ? bq : (z == 1) ? bk : bv;

    const int m0 = blockIdx.x * 128;
    const int n0 = blockIdx.y * 128;
    const int wr = (wave >> 1) * 64;
    const int wc = (wave & 1) * 64;

    const int srow = tid >> 1;
    const int scol = (tid & 1) * 16;
    const float* xsrc = x + (size_t)(m0 + srow) * ND + scol;
    const float* wsrc = W + (size_t)(n0 + srow) * ND + scol;

    const int lg = lane >> 4;
    const int ll = lane & 15;
    const int kcol = lg * 8;

    f32x4 acc[4][4] = {};

    for (int kt = 0; kt < ND; kt += 32) {
        float4 a0 = *(const float4*)(xsrc + kt);
        float4 a1 = *(const float4*)(xsrc + kt + 4);
        float4 a2 = *(const float4*)(xsrc + kt + 8);
        float4 a3 = *(const float4*)(xsrc + kt + 12);
        float4 b0 = *(const float4*)(wsrc + kt);
        float4 b1 = *(const float4*)(wsrc + kt + 4);
        float4 b2 = *(const float4*)(wsrc + kt + 8);
        float4 b3 = *(const float4*)(wsrc + kt + 12);

        if (kt != 0) __syncthreads();
        cvt16(a0, a1, a2, a3, &Alds[srow][scol]);
        cvt16(b0, b1, b2, b3, &Blds[srow][scol]);
        __syncthreads();

        bf16x8 af[4], bfr[4];
        #pragma unroll
        for (int m = 0; m < 4; m++)
            af[m] = *(const bf16x8*)&Alds[wr + m * 16 + ll][kcol];
        #pragma unroll
        for (int n = 0; n < 4; n++)
            bfr[n] = *(const bf16x8*)&Blds[wc + n * 16 + ll][kcol];

        #pragma unroll
        for (int m = 0; m < 4; m++)
            #pragma unroll
            for (int n = 0; n < 4; n++)
                acc[m][n] = __builtin_amdgcn_mfma_f32_16x16x32_bf16(
                    af[m], bfr[n], acc[m][n], 0, 0, 0);
    }

    #pragma unroll
    for (int n = 0; n < 4; n++) {
        const int j  = n0 + wc + n * 16 + ll;
        const float bj = bias[j];
        const int hh = j >> 6;
        const int hd = j & 63;
        #pragma unroll
        for (int m = 0; m < 4; m++) {
            #pragma unroll
            for (int r = 0; r < 4; r++) {
                const int i  = m0 + wr + m * 16 + lg * 4 + r;
                const int bb = i >> 11;
                const int ss = i & 2047;
                const unsigned short o = f2b(acc[m][n][r] + bj);
                if (z == 2) {
                    Vtb[((size_t)(bb * NH + hh) * NHD + hd) * NS + ss] = o;
                } else {
                    const size_t idx = ((size_t)(bb * NH + hh) * NS + ss) * NHD + hd;
                    if (z == 0) Qb[idx] = o; else Kb[idx] = o;
                }
            }
        }
    }
}

// ---------------------------------------------------------------------------
// Flash attention: one wave per 16 q-rows, 4 waves/block, KVBLK=64.
// Mask from bit-packed words (1 u64 per row-chunk). Plds padded to 72 shorts
// per row (144 B) -> 2-way banks on both write and A-frag read (free).
// ---------------------------------------------------------------------------
__global__ __launch_bounds__(256) void attn_kernel(
    const unsigned short* __restrict__ Qb, const unsigned short* __restrict__ Kb,
    const unsigned short* __restrict__ Vtb,
    const unsigned long long* __restrict__ mbits, float* __restrict__ out)
{
    __shared__ alignas(16) unsigned short Plds[4][16][72];

    const int tid  = threadIdx.x;
    const int wave = tid >> 6;
    const int lane = tid & 63;
    const int b = blockIdx.z;
    const int h = blockIdx.y;
    const int q0 = blockIdx.x * 64 + wave * 16;

    const unsigned short* Qp = Qb  + (size_t)(b * NH + h) * NS * NHD;
    const unsigned short* Kp = Kb  + (size_t)(b * NH + h) * NS * NHD;
    const unsigned short* Vp = Vtb + (size_t)(b * NH + h) * NHD * NS;
    const unsigned long long* mrow = mbits + (size_t)b * NS * (NS / 64);

    const int lg = lane >> 4;
    const int ll = lane & 15;
    const int kcol = lg * 8;

    const bf16x8 qf0 = *(const bf16x8*)&Qp[(q0 + ll) * NHD + kcol];
    const bf16x8 qf1 = *(const bf16x8*)&Qp[(q0 + ll) * NHD + 32 + kcol];

    f32x4 O0 = {}, O1 = {}, O2 = {}, O3 = {};
    float mrun[4] = {-3.0e38f, -3.0e38f, -3.0e38f, -3.0e38f};
    float lrun[4] = {0.f, 0.f, 0.f, 0.f};

    const float scale = 0.03125f;  // 1/sqrt(1024)

    for (int kb = 0; kb < NS; kb += 64) {
        // ---- QK^T: four 16-key tiles ----
        f32x4 s0 = {}, s1 = {}, s2 = {}, s3 = {};
        {
            bf16x8 a = *(const bf16x8*)&Kp[(kb + ll) * NHD + kcol];
            bf16x8 c = *(const bf16x8*)&Kp[(kb + ll) * NHD + 32 + kcol];
            s0 = __builtin_amdgcn_mfma_f32_16x16x32_bf16(qf0, a, s0, 0, 0, 0);
            s0 = __builtin_amdgcn_mfma_f32_16x16x32_bf16(qf1, c, s0, 0, 0, 0);
        }
        {
            bf16x8 a = *(const bf16x8*)&Kp[(kb + 16 + ll) * NHD + kcol];
            bf16x8 c = *(const bf16x8*)&Kp[(kb + 16 + ll) * NHD + 32 + kcol];
            s1 = __builtin_amdgcn_mfma_f32_16x16x32_bf16(qf0, a, s1, 0, 0, 0);
            s1 = __builtin_amdgcn_mfma_f32_16x16x32_bf16(qf1, c, s1, 0, 0, 0);
        }
        {
            bf16x8 a = *(const bf16x8*)&Kp[(kb + 32 + ll) * NHD + kcol];
            bf16x8 c = *(const bf16x8*)&Kp[(kb + 32 + ll) * NHD + 32 + kcol];
            s2 = __builtin_amdgcn_mfma_f32_16x16x32_bf16(qf0, a, s2, 0, 0, 0);
            s2 = __builtin_amdgcn_mfma_f32_16x16x32_bf16(qf1, c, s2, 0, 0, 0);
        }
        {
            bf16x8 a = *(const bf16x8*)&Kp[(kb + 48 + ll) * NHD + kcol];
            bf16x8 c = *(const bf16x8*)&Kp[(kb + 48 + ll) * NHD + 32 + kcol];
            s3 = __builtin_amdgcn_mfma_f32_16x16x32_bf16(qf0, a, s3, 0, 0, 0);
            s3 = __builtin_amdgcn_mfma_f32_16x16x32_bf16(qf1, c, s3, 0, 0, 0);
        }

        // ---- mask words: one u64 covers this row's 64 keys ----
        unsigned long long mw[4];
        #pragma unroll
        for (int r = 0; r < 4; r++)
            mw[r] = mrow[(size_t)(q0 + lg * 4 + r) * (NS / 64) + (kb >> 6)];

        // ---- online softmax, one pass over 64 keys ----
        #pragma unroll
        for (int r = 0; r < 4; r++) {
            const unsigned lo = (unsigned)mw[r];
            const unsigned hi = (unsigned)(mw[r] >> 32);
            float sv0 = ((lo >> ll)        & 1u) ? -1e9f : s0[r] * scale;
            float sv1 = ((lo >> (16 + ll)) & 1u) ? -1e9f : s1[r] * scale;
            float sv2 = ((hi >> ll)        & 1u) ? -1e9f : s2[r] * scale;
            float sv3 = ((hi >> (16 + ll)) & 1u) ? -1e9f : s3[r] * scale;

            float mt = fmaxf(fmaxf(sv0, sv1), fmaxf(sv2, sv3));
            mt = fmaxf(mt, __shfl_xor(mt, 1));
            mt = fmaxf(mt, __shfl_xor(mt, 2));
            mt = fmaxf(mt, __shfl_xor(mt, 4));
            mt = fmaxf(mt, __shfl_xor(mt, 8));

            const float mnew  = fmaxf(mrun[r], mt);
            const float alpha = __expf(mrun[r] - mnew);
            const float p0 = __expf(sv0 - mnew);
            const float p1 = __expf(sv1 - mnew);
            const float p2 = __expf(sv2 - mnew);
            const float p3 = __expf(sv3 - mnew);

            float rs = (p0 + p1) + (p2 + p3);
            rs += __shfl_xor(rs, 1);
            rs += __shfl_xor(rs, 2);
            rs += __shfl_xor(rs, 4);
            rs += __shfl_xor(rs, 8);

            lrun[r] = lrun[r] * alpha + rs;
            mrun[r] = mnew;
            O0[r] *= alpha; O1[r] *= alpha; O2[r] *= alpha; O3[r] *= alpha;

            const int prow = lg * 4 + r;
            Plds[wave][prow][ll]      = f2b(p0);
            Plds[wave][prow][16 + ll] = f2b(p1);
            Plds[wave][prow][32 + ll] = f2b(p2);
            Plds[wave][prow][48 + ll] = f2b(p3);
        }

        // ---- PV: A = P[16 q][64 k], two k-steps; B = V^T fragments ----
        const bf16x8 pa0 = *(const bf16x8*)&Plds[wave][ll][kcol];
        const bf16x8 pa1 = *(const bf16x8*)&Plds[wave][ll][32 + kcol];
        #pragma unroll
        for (int d = 0; d < 4; d++) {
            const bf16x8 v0 = *(const bf16x8*)&Vp[(size_t)(d * 16 + ll) * NS + kb + kcol];
            const bf16x8 v1 = *(const bf16x8*)&Vp[(size_t)(d * 16 + ll) * NS + kb + 32 + kcol];
            f32x4& Od = (d == 0) ? O0 : (d == 1) ? O1 : (d == 2) ? O2 : O3;
            Od = __builtin_amdgcn_mfma_f32_16x16x32_bf16(pa0, v0, Od, 0, 0, 0);
            Od = __builtin_amdgcn_mfma_f32_16x16x32_bf16(pa1, v1, Od, 0, 0, 0);
        }
    }

    #pragma unroll
    for (int r = 0; r < 4; r++) {
        const int q = q0 + lg * 4 + r;
        const float inv = 1.0f / lrun[r];
        float* op = out + (size_t)(b * NS + q) * ND + h * NHD;
        op[0 * 16 + ll] = O0[r] * inv;
        op[1 * 16 + ll] = O1[r] * inv;
        op[2 * 16 + ll] = O2[r] * inv;
        op[3 * 16 + ll] = O3[r] * inv;
    }
}

extern "C" void kernel_launch(void* const* d_in, const int* in_sizes, int n_in,
                              void* d_out, int out_size, void* d_ws, size_t ws_size,
                              hipStream_t stream)
{
    const float* x  = (const float*)d_in[0];
    const void* mask = d_in[1];
    const float* Wq = (const float*)d_in[2];
    const float* bq = (const float*)d_in[3];
    const float* Wk = (const float*)d_in[4];
    const float* bk = (const float*)d_in[5];
    const float* Wv = (const float*)d_in[6];
    const float* bv = (const float*)d_in[7];
    float* out = (float*)d_out;

    int* mflag = (int*)d_ws;
    unsigned short* Qb  = (unsigned short*)((char*)d_ws + 256);   // 8MB
    unsigned short* Kb  = Qb + (size_t)NB * NH * NS * NHD;        // 8MB
    unsigned short* Vtb = Kb + (size_t)NB * NH * NS * NHD;        // 8MB (transposed)
    unsigned long long* mbits =
        (unsigned long long*)(Vtb + (size_t)NB * NH * NHD * NS);  // 1MB

    dim3 blk(256);
    detect_mask<<<dim3(1), blk, 0, stream>>>((const unsigned*)mask, mflag);

    const int words = NB * NS * NS / 64;
    pack_mask<<<dim3(words / 4), blk, 0, stream>>>(mask, mflag, mbits);

    dim3 g1(32, 8, 3);
    qkv_gemm<<<g1, blk, 0, stream>>>(x, Wq, bq, Wk, bk, Wv, bv, Qb, Kb, Vtb);

    dim3 g2(NS / 64, NH, NB);
    attn_kernel<<<g2, blk, 0, stream>>>(Qb, Kb, Vtb, mbits, out);
}